// Round 4
// baseline (54564.612 us; speedup 1.0000x reference)
//
#include <hip/hip_runtime.h>
#include <cmath>

// LIF_complex round 4: event-driven sparse recurrence.
// u(t) = W@g(t) is maintained incrementally:
//   u(t) = a0*u(t-1) + sum_{published j} w[:,j] * c_j,
//   c_j = g(t)_j - a0*g(t-1)_j,  a0 = 1 - 1/tau_g[0].
// c_j == 0 (up to ulp) for non-spiking neurons with tau_g_j == tau_g[0], so
// only spiking (or tau-mismatched, "always-active") neurons publish. Spike
// rate is physiologically bounded (~N/5 per step), so the per-step global
// traffic is a ~350-entry list instead of a dense 2048-float vector, and the
// per-step compute is ~350x16 MACs/block instead of 2048x16.
// 128 blocks x 256 threads; block owns 16 rows; w rows live TRANSPOSED in
// LDS (stride 17 to break bank alignment) -- no VGPR-pinning games (rounds
// 1-3 all lost to the register allocator: VGPR_Count 56/60/40).
// Dataflow sync, no barrier: per-block record = header {tag|count} + <=16
// entries {tag,j|c}; tag-in-entry makes entries self-validating, so no
// release/acquire ordering is needed; double-buffered by step parity.
// Reuse safety: a block publishes step t (overwriting t-2 slots) only after
// observing all t-1 headers, which certifies every block fetched its t-2
// entries (fetch precedes that block's t-1 publish via two __syncthreads).

#define T_STEPS 8192
#define NN      2048
#define NBLK    128
#define NTHR    256
#define RPB     16    // rows (neurons) per block
#define WPR     16    // worker lanes per row
#define WSTR    17    // padded LDS stride for transposed w
#define DUMP    32    // steps buffered before an output dump

typedef unsigned long long u64;

__device__ __forceinline__ float stable_sigmoid(float x) {
    if (x >= 0.0f) {
        return 1.0f / (1.0f + expf(-x));
    } else {
        float e = expf(x);
        return e / (1.0f + e);
    }
}

__global__ __launch_bounds__(NTHR, 1) void lif_kernel(
    const float* __restrict__ x_in,    // [T, N]
    const float* __restrict__ w,       // [N, N]
    const float* __restrict__ v_rest,  // [N]
    const float* __restrict__ tau_m,   // [N]
    const float* __restrict__ tau_g,   // [N]
    const float* __restrict__ pre_cp,  // [1]
    const float* __restrict__ post_cp, // [1]
    const float* __restrict__ v0,      // [N]
    const float* __restrict__ g0,      // [N]
    float* __restrict__ out,           // [2, T, N]
    u64* __restrict__ hdr,             // [2][NBLK]      (ws)
    u64* __restrict__ ent)             // [2][NBLK*RPB]  (ws)
{
    __shared__ float    wT[NN * WSTR];      // 139264 B, wT[j*17 + r]
    __shared__ u64      jc[2048];           // 16384 B: two 1024-entry regions
    __shared__ float    vbuf[DUMP][RPB];    // 2048 B
    __shared__ float    sbuf[DUMP][RPB];    // 2048 B
    __shared__ float    sc_s[RPB];
    __shared__ unsigned sflag_s[RPB];
    __shared__ unsigned ntot_s[2];

    const int tid = threadIdx.x;
    const int b   = blockIdx.x;
    const int r   = tid >> 4;          // row 0..15
    const int k   = tid & 15;          // worker lane within row
    const int n   = b * RPB + r;
    const bool leader = (k == 0);

    // ---- stage w rows (transposed) into LDS, coalesced float4 reads
    for (int rr = 0; rr < RPB; ++rr) {
        const float4* row4 = (const float4*)(w + (size_t)(b * RPB + rr) * NN);
        for (int q = tid; q < NN / 4; q += NTHR) {
            float4 f = row4[q];
            wT[(4 * q + 0) * WSTR + rr] = f.x;
            wT[(4 * q + 1) * WSTR + rr] = f.y;
            wT[(4 * q + 2) * WSTR + rr] = f.z;
            wT[(4 * q + 3) * WSTR + rr] = f.w;
        }
    }
    // stage g0 (reuse jc space as float scratch)
    float* g0s = (float*)jc;
    for (int q = tid; q < NN; q += NTHR) g0s[q] = g0[q];
    __syncthreads();

    const float pre_c  = pre_cp[0];
    const float post_c = post_cp[0];
    const float tg0    = tau_g[0];
    const float a0     = 1.0f - 1.0f / tg0;

    // ---- u_init = W @ g0 (dense, once)
    float p0 = 0.0f;
    for (int j = k; j < NN; j += WPR)
        p0 = fmaf(g0s[j], wT[j * WSTR + r], p0);
#pragma unroll
    for (int m = 1; m < WPR; m <<= 1) p0 += __shfl_xor(p0, m, 64);

    float vr = 0.f, tm = 1.f, tg = 1.f, v = 0.f, g = 0.f, u = 0.f;
    bool act = false;
    if (leader) {
        vr = v_rest[n]; tm = tau_m[n]; tg = tau_g[n];
        v  = v0[n];     g  = g0[n];    u  = p0;
        act = (__float_as_uint(tg) != __float_as_uint(tg0)); // tau-mismatch
    }

    for (int t = 0; t < T_STEPS; ++t) {
        float x = 0.0f;
        if (leader) x = x_in[(size_t)t * NN + n];  // issued before the polls

        if (t > 0) {
            const int par = (t - 1) & 1;
            const unsigned want = (unsigned)(t - 1);
            unsigned cnt = 0;
            if (tid < NBLK) {
                const u64* hp = hdr + (size_t)par * NBLK + tid;
                u64 hv = __hip_atomic_load(hp, __ATOMIC_RELAXED,
                                           __HIP_MEMORY_SCOPE_AGENT);
                while ((unsigned)(hv >> 32) != want)
                    hv = __hip_atomic_load(hp, __ATOMIC_RELAXED,
                                           __HIP_MEMORY_SCOPE_AGENT);
                cnt = (unsigned)hv;
            }
            // intra-wave inclusive scan of counts (records 0..63 wave0,
            // 64..127 wave1; waves 2/3 scan zeros, harmless)
            unsigned xs = cnt;
#pragma unroll
            for (int d = 1; d < 64; d <<= 1) {
                unsigned nb = __shfl_up(xs, (unsigned)d, 64);
                if ((tid & 63) >= d) xs += nb;
            }
            if ((tid & 63) == 63 && (tid >> 6) < 2) ntot_s[tid >> 6] = xs;
            const unsigned mybase = (unsigned)((tid >> 6) << 10) + (xs - cnt);
            // fetch my record's entries into my region slice (self-validating)
            if (tid < NBLK && cnt) {
                const u64* ep = ent + (size_t)par * NBLK * RPB + tid * RPB;
                for (unsigned q = 0; q < cnt; ++q) {
                    u64 ev = __hip_atomic_load(ep + q, __ATOMIC_RELAXED,
                                               __HIP_MEMORY_SCOPE_AGENT);
                    while (((unsigned)(ev >> 32) >> 11) != want)
                        ev = __hip_atomic_load(ep + q, __ATOMIC_RELAXED,
                                               __HIP_MEMORY_SCOPE_AGENT);
                    jc[mybase + q] = ev;
                }
            }
            __syncthreads();

            // ---- sparse u update: walk both regions, 4-deep batched loads
            const int n0 = (int)ntot_s[0];
            const int n1 = (int)ntot_s[1];
            float p = 0.0f;
#pragma unroll
            for (int reg = 0; reg < 2; ++reg) {
                const int lim = reg ? n1 : n0;
                const int off = reg ? 1024 : 0;
                for (int i = k; i < lim; i += WPR * 4) {
                    const int i1 = i + WPR, i2 = i + 2 * WPR, i3 = i + 3 * WPR;
                    u64 e0 = jc[off + i];                       // i < lim
                    u64 e1 = (i1 < lim) ? jc[off + i1] : 0ull;  // 0 -> c=0
                    u64 e2 = (i2 < lim) ? jc[off + i2] : 0ull;
                    u64 e3 = (i3 < lim) ? jc[off + i3] : 0ull;
                    float w0 = wT[(int)((e0 >> 32) & 0x7FF) * WSTR + r];
                    float w1 = wT[(int)((e1 >> 32) & 0x7FF) * WSTR + r];
                    float w2 = wT[(int)((e2 >> 32) & 0x7FF) * WSTR + r];
                    float w3 = wT[(int)((e3 >> 32) & 0x7FF) * WSTR + r];
                    p = fmaf(__uint_as_float((unsigned)e0), w0, p);
                    p = fmaf(__uint_as_float((unsigned)e1), w1, p);
                    p = fmaf(__uint_as_float((unsigned)e2), w2, p);
                    p = fmaf(__uint_as_float((unsigned)e3), w3, p);
                }
            }
#pragma unroll
            for (int m = 1; m < WPR; m <<= 1) p += __shfl_xor(p, m, 64);
            if (leader) u = fmaf(a0, u, p);   // u = a0*u + sparse adds
        }

        // ---- neuron update (exact reference trajectory for v, g)
        if (leader) {
            float I = post_c * stable_sigmoid(pre_c * (u + x));
            float gprev = g;
            g = g - g / tg;
            v = v + (vr - v + I) / tm;
            float soft = stable_sigmoid(v - 30.0f);
            bool  spk  = (v >= 30.0f);
            v = spk ? vr : v;
            g = spk ? 1.0f : g;
            vbuf[t & (DUMP - 1)][r] = v;
            sbuf[t & (DUMP - 1)][r] = soft;
            sc_s[r]    = g - a0 * gprev;                 // publish coefficient
            sflag_s[r] = (spk || act) ? 1u : 0u;
        }
        __syncthreads();

        // ---- publish this block's record (wave 0)
        if (tid < 64) {
            unsigned f = (tid < RPB) ? sflag_s[tid] : 0u;
            u64 m = __ballot(f != 0u);
            if (tid < RPB && f) {
                int pos = __popcll(m & ((1ull << tid) - 1ull));
                u64 ev = ((u64)(((unsigned)t << 11) | (unsigned)(b * RPB + tid))
                          << 32) | (u64)__float_as_uint(sc_s[tid]);
                __hip_atomic_store(ent + (size_t)(t & 1) * NBLK * RPB
                                       + b * RPB + pos, ev,
                                   __ATOMIC_RELAXED, __HIP_MEMORY_SCOPE_AGENT);
            }
            if (tid == 0) {
                u64 hv = ((u64)(unsigned)t << 32) | (unsigned)__popcll(m);
                __hip_atomic_store(hdr + (size_t)(t & 1) * NBLK + b, hv,
                                   __ATOMIC_RELAXED, __HIP_MEMORY_SCOPE_AGENT);
            }
        }

        // ---- coalesced output dump every DUMP steps
        if ((t & (DUMP - 1)) == (DUMP - 1)) {
            const int t0 = t - (DUMP - 1);
#pragma unroll
            for (int q = 0; q < (DUMP * RPB) / NTHR; ++q) {
                int e  = tid + NTHR * q;
                int s  = e >> 4;
                int rr = e & 15;
                size_t o = (size_t)(t0 + s) * NN + b * RPB + rr;
                out[o] = vbuf[s][rr];
                out[(size_t)T_STEPS * NN + o] = sbuf[s][rr];
            }
        }
    }
}

extern "C" void kernel_launch(void* const* d_in, const int* in_sizes, int n_in,
                              void* d_out, int out_size, void* d_ws, size_t ws_size,
                              hipStream_t stream) {
    const float* x_in   = (const float*)d_in[0];
    const float* w      = (const float*)d_in[1];
    const float* v_rest = (const float*)d_in[2];
    const float* tau_m  = (const float*)d_in[3];
    const float* tau_g  = (const float*)d_in[4];
    const float* pre_c  = (const float*)d_in[5];
    const float* post_c = (const float*)d_in[6];
    const float* v0     = (const float*)d_in[7];
    const float* g0     = (const float*)d_in[8];
    float* out = (float*)d_out;

    u64* hdr = (u64*)d_ws;                 // [2][NBLK]
    u64* ent = hdr + 2 * NBLK;             // [2][NBLK*RPB]

    // 0xFF fill -> header tag 0xFFFFFFFF and entry tag 0x1FFFFF never match
    // any t in [0, 8192)
    hipMemsetAsync(d_ws, 0xFF, (2 * NBLK + 2 * NBLK * RPB) * sizeof(u64),
                   stream);

    void* args[] = {
        (void*)&x_in, (void*)&w, (void*)&v_rest, (void*)&tau_m, (void*)&tau_g,
        (void*)&pre_c, (void*)&post_c, (void*)&v0, (void*)&g0,
        (void*)&out, (void*)&hdr, (void*)&ent
    };
    hipLaunchCooperativeKernel((void*)lif_kernel, dim3(NBLK), dim3(NTHR),
                               args, 0, stream);
}

// Round 5
// 23891.576 us; speedup vs baseline: 2.2838x; 2.2838x over previous
//
#include <hip/hip_runtime.h>
#include <cmath>

// LIF_complex round 5: dense single-hop broadcast (round-3 skeleton) with
//  (a) w in 8 NAMED float4 registers per thread (no arrays -> no scratch;
//      rounds 1-3 lost the allocator fight with array+pin tricks),
//  (b) 2-D wave tiling: wave (i,j) = rows 4i..4i+3 x cols 512j..512j+511,
//      so each lane reads 32 B of g from LDS instead of 128 B (LDS dot
//      traffic 128 KB -> 32 KB per block-step),
//  (c) gs double-buffered (one protection barrier removed), dump behind the
//      stage barrier via parity ordering,
//  (d) s_sleep backoff in the poll loop (2 MB/round of coherence-fabric
//      poll traffic plausibly stretched store-visibility in round 3).
// Dataflow sync (proven r3): 2048 8-byte {tag=t | g bits} slots, parity
// double-buffer. Block publishes tag t only after observing ALL tags t-1,
// which certifies every block finished reading tags t-2 -> overwrite safe.
// 128 blocks x 1024 threads (16 waves), block owns 16 neurons.

#define T_STEPS 8192
#define NN      2048
#define NBLK    128
#define NTHR    1024
#define RPB     16
#define DUMP    64

typedef unsigned long long u64;

__device__ __forceinline__ float stable_sigmoid(float x) {
    if (x >= 0.0f) {
        return 1.0f / (1.0f + expf(-x));
    } else {
        float e = expf(x);
        return e / (1.0f + e);
    }
}

__global__ __launch_bounds__(NTHR, 2) void lif_kernel(
    const float* __restrict__ x_in,    // [T, N]
    const float* __restrict__ w,       // [N, N]
    const float* __restrict__ v_rest,  // [N]
    const float* __restrict__ tau_m,   // [N]
    const float* __restrict__ tau_g,   // [N]
    const float* __restrict__ pre_cp,  // [1]
    const float* __restrict__ post_cp, // [1]
    const float* __restrict__ v0,      // [N]
    const float* __restrict__ g0,      // [N]
    float* __restrict__ out,           // [2, T, N]
    u64* __restrict__ slots)           // [2, N] tagged g slots (ws)
{
    __shared__ float gs[2][NN];        // 16 KB, double-buffered g
    __shared__ float preduce[4][RPB];  // [col-group j][row]
    __shared__ float vbuf[DUMP][RPB];
    __shared__ float sbuf[DUMP][RPB];

    const int tid = threadIdx.x;
    const int b   = blockIdx.x;
    const int wv  = tid >> 6;
    const int i   = wv & 3;            // row group (4 rows)
    const int j   = wv >> 2;           // col group (512 cols)
    const int k   = tid & 63;          // lane

    // ---- w tile into named registers: rows b*16+4i..+3, cols 512j+8k..+7
    const float* wbase = w + (size_t)(b * RPB + 4 * i) * NN + 512 * j;
    const float4* r0 = (const float4*)(wbase);
    const float4* r1 = (const float4*)(wbase + NN);
    const float4* r2 = (const float4*)(wbase + 2 * NN);
    const float4* r3 = (const float4*)(wbase + 3 * NN);
    const float4 w0a = r0[2 * k], w0b = r0[2 * k + 1];
    const float4 w1a = r1[2 * k], w1b = r1[2 * k + 1];
    const float4 w2a = r2[2 * k], w2b = r2[2 * k + 1];
    const float4 w3a = r3[2 * k], w3b = r3[2 * k + 1];

    const float pre_c  = pre_cp[0];
    const float post_c = post_cp[0];

    // ---- neuron state lives in wave 0, lanes 0..15
    float vr = 0.f, tm = 1.f, tg = 1.f, v = 0.f, g = 0.f;
    if (tid < RPB) {
        const int n = b * RPB + tid;
        vr = v_rest[n]; tm = tau_m[n]; tg = tau_g[n];
        v  = v0[n];     g  = g0[n];
    }

    for (int t = 0; t < T_STEPS; ++t) {
        const int gpar = (t + 1) & 1;  // == (t-1)&1: gs buffer for g(t-1)

        // x prefetch (consumed by wave 0 after barrier B)
        float x = 0.0f;
        if (tid < RPB) x = x_in[(size_t)t * NN + b * RPB + tid];

        // ---- acquire g(t-1): one 8B tagged slot pair per thread
        if (t == 0) {
            float2 gz = ((const float2*)g0)[tid];
            ((float2*)gs[gpar])[tid] = gz;
        } else {
            const u64* sl = slots + (size_t)gpar * NN;
            const unsigned want = (unsigned)(t - 1);
            u64 A = __hip_atomic_load(sl + 2 * tid, __ATOMIC_RELAXED,
                                      __HIP_MEMORY_SCOPE_AGENT);
            u64 B = __hip_atomic_load(sl + 2 * tid + 1, __ATOMIC_RELAXED,
                                      __HIP_MEMORY_SCOPE_AGENT);
            while ((unsigned)(A >> 32) != want || (unsigned)(B >> 32) != want) {
                __builtin_amdgcn_s_sleep(1);
                A = __hip_atomic_load(sl + 2 * tid, __ATOMIC_RELAXED,
                                      __HIP_MEMORY_SCOPE_AGENT);
                B = __hip_atomic_load(sl + 2 * tid + 1, __ATOMIC_RELAXED,
                                      __HIP_MEMORY_SCOPE_AGENT);
            }
            ((float2*)gs[gpar])[tid] =
                make_float2(__uint_as_float((unsigned)A),
                            __uint_as_float((unsigned)B));
        }
        __syncthreads();  // barrier A: gs[gpar] complete

        // ---- output dump (parity-ordered: all window writes precede the
        // writers' barrier-A arrival for this step)
        if ((t & (DUMP - 1)) == 0 && t != 0) {
            const int t0 = t - DUMP;
            const int s  = tid >> 4;
            const int rr = tid & 15;
            size_t o = (size_t)(t0 + s) * NN + b * RPB + rr;
            out[o] = vbuf[s][rr];
            out[(size_t)T_STEPS * NN + o] = sbuf[s][rr];
        }

        // ---- dot: rows 4i..4i+3 x cols 512j+8k..+7, w from registers
        const float4* gs4 = (const float4*)(gs[gpar] + 512 * j);
        const float4 ga = gs4[2 * k];
        const float4 gb = gs4[2 * k + 1];
        float a0 = 0.f, a1 = 0.f, a2 = 0.f, a3 = 0.f;
#define ROWFMA(acc, wa, wb)                                   \
        acc = fmaf(wa.x, ga.x, acc); acc = fmaf(wa.y, ga.y, acc); \
        acc = fmaf(wa.z, ga.z, acc); acc = fmaf(wa.w, ga.w, acc); \
        acc = fmaf(wb.x, gb.x, acc); acc = fmaf(wb.y, gb.y, acc); \
        acc = fmaf(wb.z, gb.z, acc);  acc = fmaf(wb.w, gb.w, acc);
        ROWFMA(a0, w0a, w0b)
        ROWFMA(a1, w1a, w1b)
        ROWFMA(a2, w2a, w2b)
        ROWFMA(a3, w3a, w3b)
#undef ROWFMA
        // butterfly over the 64 lanes (col reduction within the wave)
#pragma unroll
        for (int m = 1; m < 64; m <<= 1) {
            a0 += __shfl_xor(a0, m, 64);
            a1 += __shfl_xor(a1, m, 64);
            a2 += __shfl_xor(a2, m, 64);
            a3 += __shfl_xor(a3, m, 64);
        }
        if (k == 0)
            ((float4*)preduce)[j * 4 + i] = make_float4(a0, a1, a2, a3);
        __syncthreads();  // barrier B: preduce complete

        // ---- neuron update + publish (wave 0, lanes 0..15)
        if (tid < RPB) {
            const float* pr = (const float*)preduce;
            float u = (pr[tid] + pr[tid + 16]) + (pr[tid + 32] + pr[tid + 48]);
            float I = post_c * stable_sigmoid(pre_c * (u + x));
            g = g - g / tg;
            v = v + (vr - v + I) / tm;
            float soft = stable_sigmoid(v - 30.0f);
            bool  spk  = (v >= 30.0f);
            v = spk ? vr : v;
            g = spk ? 1.0f : g;
            vbuf[t & (DUMP - 1)][tid] = v;
            sbuf[t & (DUMP - 1)][tid] = soft;
            u64 pk = ((u64)(unsigned)t << 32) | (u64)__float_as_uint(g);
            __hip_atomic_store(slots + (size_t)(t & 1) * NN + b * RPB + tid,
                               pk, __ATOMIC_RELAXED, __HIP_MEMORY_SCOPE_AGENT);
        }
        // no barrier here: next poll writes gs[other parity]; preduce is
        // rewritten only after the next barrier A; vbuf slot reuse is 64
        // steps (many barriers) away.
    }

    // ---- final window dump
    __syncthreads();
    {
        const int t0 = T_STEPS - DUMP;
        const int s  = tid >> 4;
        const int rr = tid & 15;
        size_t o = (size_t)(t0 + s) * NN + b * RPB + rr;
        out[o] = vbuf[s][rr];
        out[(size_t)T_STEPS * NN + o] = sbuf[s][rr];
    }
}

extern "C" void kernel_launch(void* const* d_in, const int* in_sizes, int n_in,
                              void* d_out, int out_size, void* d_ws, size_t ws_size,
                              hipStream_t stream) {
    const float* x_in   = (const float*)d_in[0];
    const float* w      = (const float*)d_in[1];
    const float* v_rest = (const float*)d_in[2];
    const float* tau_m  = (const float*)d_in[3];
    const float* tau_g  = (const float*)d_in[4];
    const float* pre_c  = (const float*)d_in[5];
    const float* post_c = (const float*)d_in[6];
    const float* v0     = (const float*)d_in[7];
    const float* g0     = (const float*)d_in[8];
    float* out = (float*)d_out;

    u64* slots = (u64*)d_ws;  // [2, NN]

    // tag 0xFFFFFFFF never matches any t in [0, 8192)
    hipMemsetAsync(slots, 0xFF, 2 * NN * sizeof(u64), stream);

    void* args[] = {
        (void*)&x_in, (void*)&w, (void*)&v_rest, (void*)&tau_m, (void*)&tau_g,
        (void*)&pre_c, (void*)&post_c, (void*)&v0, (void*)&g0,
        (void*)&out, (void*)&slots
    };
    hipLaunchCooperativeKernel((void*)lif_kernel, dim3(NBLK), dim3(NTHR),
                               args, 0, stream);
}